// Round 3
// baseline (109.417 us; speedup 1.0000x reference)
//
#include <hip/hip_runtime.h>
#include <hip/hip_cooperative_groups.h>

namespace cg = cooperative_groups;

// Problem constants (fixed by reference): pred/target (8,3,224,224) fp32.
#define BINS   30
#define BATCH  8
#define NB     (BATCH * BINS)    // 240 per input
#define ROW_N  150528            // 3*224*224 elements per batch row
#define ROW_N4 (ROW_N / 4)       // 37632 float4 per row
#define BPR    32                // blocks per row
#define NROWS  16                // 2 inputs * 8 batches
#define GRID   (NROWS * BPR)     // 512 blocks = 2 blocks/CU -> co-resident

// K2 = -0.5 / delta^2 * log2(e) = -450 * log2(e)
#define K2D (-649.2627684000335)
#define K2F ((float)K2D)

__global__ __launch_bounds__(256, 2) void hsim_fused_kernel(
    const float* __restrict__ pred,
    const float* __restrict__ target,
    float* __restrict__ ghist,   // [2][NB] in d_ws: pred at 0, target at NB
    float* __restrict__ out)
{
    cg::grid_group grid = cg::this_grid();

    // ---- phase 0: zero the global histogram (replaces the memset dispatch)
    if (blockIdx.x == 0) {
        for (int i = threadIdx.x; i < 2 * NB; i += 256) ghist[i] = 0.0f;
    }
    grid.sync();

    // ---- phase 1: per-block partial histograms
    const int row       = blockIdx.x / BPR;   // 0..15
    const int chunk     = blockIdx.x % BPR;
    const int input_sel = row >> 3;           // 0 = pred, 1 = target
    const int batch     = row & 7;

    const float4* src4 =
        (const float4*)((input_sel ? target : pred) + (size_t)batch * ROW_N);

    float acc[BINS];
#pragma unroll
    for (int b = 0; b < BINS; ++b) acc[b] = 0.0f;

    for (int i = chunk * 256 + threadIdx.x; i < ROW_N4; i += BPR * 256) {
        float4 v = src4[i];
        // arg_b = K2*(x-c_b)^2 = K2*x^2 + P_b*x + Q_b
        const float X0 = (v.x * K2F) * v.x;
        const float X1 = (v.y * K2F) * v.y;
        const float X2 = (v.z * K2F) * v.z;
        const float X3 = (v.w * K2F) * v.w;
#pragma unroll
        for (int b = 0; b < BINS; ++b) {
            const double cd = (b + 0.5) / 30.0;
            const float  P  = (float)(-2.0 * K2D * cd);  // SGPR constant
            const float  Q  = (float)(K2D * cd * cd);    // VOP2 literal
            acc[b] += __builtin_amdgcn_exp2f(fmaf(v.x, P, X0) + Q);
            acc[b] += __builtin_amdgcn_exp2f(fmaf(v.y, P, X1) + Q);
            acc[b] += __builtin_amdgcn_exp2f(fmaf(v.z, P, X2) + Q);
            acc[b] += __builtin_amdgcn_exp2f(fmaf(v.w, P, X3) + Q);
        }
    }

    // Wave-level butterfly reduce each bin across 64 lanes.
#pragma unroll
    for (int b = 0; b < BINS; ++b) {
        float v = acc[b];
#pragma unroll
        for (int off = 32; off >= 1; off >>= 1)
            v += __shfl_xor(v, off, 64);
        acc[b] = v;
    }

    __shared__ float lhist[BINS];
    if (threadIdx.x < BINS) lhist[threadIdx.x] = 0.0f;
    __syncthreads();

    if ((threadIdx.x & 63) == 0) {   // one lane per wave (4 waves)
#pragma unroll
        for (int b = 0; b < BINS; ++b) atomicAdd(&lhist[b], acc[b]);
    }
    __syncthreads();

    if (threadIdx.x < BINS) {
        atomicAdd(&ghist[input_sel * NB + batch * BINS + threadIdx.x],
                  lhist[threadIdx.x]);
    }

    grid.sync();

    // ---- phase 2: block 0 computes the score
    if (blockIdx.x == 0) {
        const int t = threadIdx.x;
        float term = 0.0f;
        if (t < NB) {
            // coherent read-back (device-scope atomic) -- avoids any stale-L1
            // concern across XCDs after the atomic accumulation phase
            const float p  = atomicAdd(&ghist[t], 0.0f);
            const float tt = atomicAdd(&ghist[NB + t], 0.0f);
            const float m  = fminf(p, tt);
            const float pd = (p == 0.0f) ? 1.0f : p;
            term = m / pd;
        }
#pragma unroll
        for (int off = 32; off >= 1; off >>= 1)
            term += __shfl_xor(term, off, 64);

        __shared__ float ws[4];
        if ((t & 63) == 0) ws[t >> 6] = term;
        __syncthreads();
        if (t == 0)
            out[0] = (ws[0] + ws[1] + ws[2] + ws[3]) * (1.0f / (float)NB);
    }
}

extern "C" void kernel_launch(void* const* d_in, const int* in_sizes, int n_in,
                              void* d_out, int out_size, void* d_ws, size_t ws_size,
                              hipStream_t stream) {
    const float* pred   = (const float*)d_in[0];
    const float* target = (const float*)d_in[1];
    float*       ghist  = (float*)d_ws;     // 480 floats of scratch
    float*       out    = (float*)d_out;

    void* args[] = { (void*)&pred, (void*)&target, (void*)&ghist, (void*)&out };
    hipLaunchCooperativeKernel((const void*)hsim_fused_kernel,
                               dim3(GRID), dim3(256), args, 0, stream);
}

// Round 4
// 32.178 us; speedup vs baseline: 3.4004x; 3.4004x over previous
//
#include <hip/hip_runtime.h>

// Problem constants (fixed by reference): pred/target (8,3,224,224) fp32.
#define BINS   30
#define BATCH  8
#define NB     (BATCH * BINS)    // 240 per input
#define ROW_N  150528            // 3*224*224 elements per batch row
#define ROW_N4 (ROW_N / 4)       // 37632 float4 per row
#define NROWS  16                // 2 inputs * 8 batches

// K2 = -0.5 / delta^2 * log2(e) = -450 * log2(e)
#define K2D (-649.2627684000335)
#define K2F ((float)K2D)

// Each block computes a 30-bin partial histogram for (row, chunk) and STORES
// it to its own slot in d_ws (no zero-init, no atomics -> no memset dispatch).
__global__ __launch_bounds__(256) void hsim_hist_kernel(
    const float* __restrict__ pred,
    const float* __restrict__ target,
    float* __restrict__ partials,   // [NROWS*BPR][BINS]
    int lg_bpr)                     // log2(blocks per row)
{
    const int bpr       = 1 << lg_bpr;
    const int row       = blockIdx.x >> lg_bpr;     // 0..15
    const int chunk     = blockIdx.x & (bpr - 1);
    const int input_sel = row >> 3;                 // 0 = pred, 1 = target
    const int batch     = row & 7;

    const float4* src4 =
        (const float4*)((input_sel ? target : pred) + (size_t)batch * ROW_N);

    float acc[BINS];
#pragma unroll
    for (int b = 0; b < BINS; ++b) acc[b] = 0.0f;

    for (int i = chunk * 256 + threadIdx.x; i < ROW_N4; i += (bpr << 8)) {
        float4 v = src4[i];
        // arg_b = K2*(x-c_b)^2 = K2*x^2 + P_b*x + Q_b
        const float X0 = (v.x * K2F) * v.x;
        const float X1 = (v.y * K2F) * v.y;
        const float X2 = (v.z * K2F) * v.z;
        const float X3 = (v.w * K2F) * v.w;
#pragma unroll
        for (int b = 0; b < BINS; ++b) {
            const double cd = (b + 0.5) / 30.0;
            const float  P  = (float)(-2.0 * K2D * cd);  // SGPR constant
            const float  Q  = (float)(K2D * cd * cd);    // VOP2 literal
            acc[b] += __builtin_amdgcn_exp2f(fmaf(v.x, P, X0) + Q);
            acc[b] += __builtin_amdgcn_exp2f(fmaf(v.y, P, X1) + Q);
            acc[b] += __builtin_amdgcn_exp2f(fmaf(v.z, P, X2) + Q);
            acc[b] += __builtin_amdgcn_exp2f(fmaf(v.w, P, X3) + Q);
        }
    }

    // Wave-level butterfly reduce each bin across 64 lanes.
#pragma unroll
    for (int b = 0; b < BINS; ++b) {
        float v = acc[b];
#pragma unroll
        for (int off = 32; off >= 1; off >>= 1)
            v += __shfl_xor(v, off, 64);
        acc[b] = v;
    }

    __shared__ float lhist[BINS];
    if (threadIdx.x < BINS) lhist[threadIdx.x] = 0.0f;
    __syncthreads();

    if ((threadIdx.x & 63) == 0) {   // one lane per wave (4 waves)
#pragma unroll
        for (int b = 0; b < BINS; ++b) atomicAdd(&lhist[b], acc[b]);
    }
    __syncthreads();

    if (threadIdx.x < BINS)
        partials[(size_t)blockIdx.x * BINS + threadIdx.x] = lhist[threadIdx.x];
}

// One block: reduce partials -> per-(batch,bin) hists -> score.
__global__ __launch_bounds__(256) void hsim_score_kernel(
    const float* __restrict__ partials, float* __restrict__ out, int lg_bpr)
{
    const int bpr = 1 << lg_bpr;
    const int t   = threadIdx.x;

    float term = 0.0f;
    if (t < NB) {                       // 240 active threads
        const int batch = t / BINS;
        const int bin   = t % BINS;
        float p = 0.0f, tg = 0.0f;
        for (int c = 0; c < bpr; ++c) {
            p  += partials[(size_t)((batch      ) * bpr + c) * BINS + bin];
            tg += partials[(size_t)((batch + 8  ) * bpr + c) * BINS + bin];
        }
        const float m  = fminf(p, tg);
        const float pd = (p == 0.0f) ? 1.0f : p;
        term = m / pd;
    }
#pragma unroll
    for (int off = 32; off >= 1; off >>= 1)
        term += __shfl_xor(term, off, 64);

    __shared__ float ws[4];
    if ((t & 63) == 0) ws[t >> 6] = term;
    __syncthreads();
    if (t == 0)
        out[0] = (ws[0] + ws[1] + ws[2] + ws[3]) * (1.0f / (float)NB);
}

extern "C" void kernel_launch(void* const* d_in, const int* in_sizes, int n_in,
                              void* d_out, int out_size, void* d_ws, size_t ws_size,
                              hipStream_t stream) {
    const float* pred   = (const float*)d_in[0];
    const float* target = (const float*)d_in[1];
    float*       parts  = (float*)d_ws;
    float*       out    = (float*)d_out;

    // Pick blocks-per-row by available scratch (deterministic: ws_size fixed).
    int lg_bpr = 5;                                  // 512 blocks, 61.4 KB
    if (ws_size < (size_t)NROWS * (1 << 5) * BINS * sizeof(float))
        lg_bpr = 3;                                  // 128 blocks, 15.4 KB

    const int grid = NROWS << lg_bpr;
    hsim_hist_kernel<<<grid, 256, 0, stream>>>(pred, target, parts, lg_bpr);
    hsim_score_kernel<<<1, 256, 0, stream>>>(parts, out, lg_bpr);
}